// Round 13
// baseline (584.853 us; speedup 1.0000x reference)
//
#include <hip/hip_runtime.h>
#include <hip/hip_bf16.h>

#define B_ 8
#define T_ 2048
#define C_ 1024
#define H_ 16
#define S_ 64
#define BT_ (B_*T_)   // 16384
#define FF_ (4*C_)    // 4096
#define NC_ 32        // chunks per sequence (T/64)

typedef __attribute__((ext_vector_type(8))) short short8;
typedef __attribute__((ext_vector_type(4))) float f32x4;
typedef __attribute__((ext_vector_type(16))) float f32x16;

union U8 { uint4 v; unsigned short s[8]; };

static __device__ __forceinline__ unsigned short f2bf(float f){
  unsigned u = __float_as_uint(f);
  unsigned r = (u + 0x7fffu + ((u >> 16) & 1u)) >> 16;
  return (unsigned short)r;
}
static __device__ __forceinline__ float bf2f(unsigned short u){
  return __uint_as_float(((unsigned)u) << 16);
}

// async global->LDS, 16B per lane; LDS dest = wave-uniform base + lane*16
static __device__ __forceinline__ void gll16(const unsigned short* g, unsigned short* l){
  __builtin_amdgcn_global_load_lds((const __attribute__((address_space(1))) void*)g,
                                   (__attribute__((address_space(3))) void*)l, 16, 0, 0);
}

// ---------------- LayerNorm: fp32 in -> bf16 out ----------------
__global__ __launch_bounds__(256) void ln_kernel(const float* __restrict__ x,
    const float* __restrict__ g, const float* __restrict__ b,
    unsigned short* __restrict__ out){
  int row = blockIdx.x;
  int tid = threadIdx.x;
  const float4* xr = reinterpret_cast<const float4*>(x + (size_t)row * C_);
  float4 v = xr[tid];
  float s = v.x + v.y + v.z + v.w;
  float q = v.x*v.x + v.y*v.y + v.z*v.z + v.w*v.w;
  int lane = tid & 63, w = tid >> 6;
  #pragma unroll
  for (int off = 32; off; off >>= 1){ s += __shfl_down(s, off); q += __shfl_down(q, off); }
  __shared__ float red[2][4];
  if (lane == 0){ red[0][w] = s; red[1][w] = q; }
  __syncthreads();
  s = red[0][0] + red[0][1] + red[0][2] + red[0][3];
  q = red[1][0] + red[1][1] + red[1][2] + red[1][3];
  float mean = s * (1.0f / C_);
  float var  = q * (1.0f / C_) - mean * mean;
  float inv = rsqrtf(var + 1e-5f);
  float4 gg = reinterpret_cast<const float4*>(g)[tid];
  float4 bb = reinterpret_cast<const float4*>(b)[tid];
  ushort4 o;
  o.x = f2bf((v.x - mean) * inv * gg.x + bb.x);
  o.y = f2bf((v.y - mean) * inv * gg.y + bb.y);
  o.z = f2bf((v.z - mean) * inv * gg.z + bb.z);
  o.w = f2bf((v.w - mean) * inv * gg.w + bb.w);
  reinterpret_cast<ushort4*>(out + (size_t)row * C_)[tid] = o;
}

// ---------------- merged weight convert+transpose: 6 weights, one launch ----------------
// blocks [0,4096): w_r/w_k/w_v/w_o (1024x1024 each); [4096,8192): w_fk (1024x4096);
// [8192,12288): w_fv (4096x1024). w[K][N] f32 -> wt[N][K] bf16.
__global__ __launch_bounds__(256) void wconv6_kernel(
    const float* __restrict__ w0, const float* __restrict__ w1,
    const float* __restrict__ w2, const float* __restrict__ w3,
    const float* __restrict__ w4, const float* __restrict__ w5,
    unsigned short* __restrict__ d0, unsigned short* __restrict__ d1,
    unsigned short* __restrict__ d2, unsigned short* __restrict__ d3,
    unsigned short* __restrict__ d4, unsigned short* __restrict__ d5){
  __shared__ float tile[32][33];
  const int idx = blockIdx.x;
  const float* w; unsigned short* wt; int K, N, bk, bn;
  if (idx < 4096){
    int which = idx >> 10, i = idx & 1023;
    w  = which==0 ? w0 : which==1 ? w1 : which==2 ? w2 : w3;
    wt = which==0 ? d0 : which==1 ? d1 : which==2 ? d2 : d3;
    K = 1024; N = 1024;
    bk = (i & 31) * 32; bn = (i >> 5) * 32;
  } else if (idx < 8192){
    int i = idx - 4096;
    w = w4; wt = d4; K = 1024; N = 4096;
    bk = (i & 31) * 32; bn = (i >> 5) * 32;
  } else {
    int i = idx - 8192;
    w = w5; wt = d5; K = 4096; N = 1024;
    bk = (i & 127) * 32; bn = (i >> 7) * 32;
  }
  int tx = threadIdx.x & 31, ty = threadIdx.x >> 5; // ty 0..7
  #pragma unroll
  for (int i = 0; i < 4; i++)
    tile[ty + 8*i][tx] = w[(size_t)(bk + ty + 8*i) * N + bn + tx];
  __syncthreads();
  #pragma unroll
  for (int i = 0; i < 4; i++)
    wt[(size_t)(bn + ty + 8*i) * K + bk + tx] = f2bf(tile[tx][ty + 8*i]);
}

// ---------------- 256x256 bf16 MFMA GEMM, BK=64, 2-phase counted-vmcnt pipeline ----------------
// Round-10 proven schedule; fragments switched to mfma_f32_32x32x16_bf16 (17% fewer
// MFMA-pipe cycles per FLOP, half the MFMA instruction count; LDS traffic identical).
// out = A[M,K] @ Bt[N,K]^T. 512 threads = 8 waves (2M x 4N), per-wave C = 128x64
//   = 4x2 fragments of 32x32. LDS: 2 buf x [256][64] x 2 ops = 128 KB -> 1 block/CU.
// Swizzle: rows 128 B; 16B-slot s at row r stored at s ^ (r&7) (pre-swizzled gll source,
//   same XOR on frag reads) -> conflict-free in 8-row stripes.
// Ledger (per wave; A-P0={rows 0-63,128-191} = frag rows mf0-1, A-P1={64-127,192-255} = mf2-3):
//   ph1 of kt: read all B + A mf0-1; issue A-P1(kt+1)->nbf [2]; 16 MFMA;
//              vmcnt(8) forces A-P1(kt); lgkm(0); barrier.
//   ph2 of kt: read A mf2-3; issue A-P0(kt+2)+B(kt+2)->bf [6] (dead regions); 16 MFMA;
//              vmcnt(8) forces A-P0(kt+1)+B(kt+1); lgkm(0); barrier.
// 32x32x16 layouts (verified m74/m101): A/B operand: row|col = lane&31, k = (lane>>5)*8+j;
//   C/D: col = lane&31, row = (reg&3) + 8*(reg>>2) + 4*(lane>>5).
// __launch_bounds__(512,2): <=256 VGPR, no spill. 128^2 tile measured slower (round 11).
#define EPI_RKV3 1
#define EPI_WO   2
#define EPI_FK   3
#define EPI_FV   4

template<int EPI>
__global__ __launch_bounds__(512, 2) void gemm64_kernel(
    const unsigned short* __restrict__ A,   // [M,K] bf16 row-major
    const unsigned short* __restrict__ Bt,  // [N,K] bf16 row-major
    void* __restrict__ outp,
    const float* __restrict__ aux,
    int K, int nx){
  __shared__ unsigned short As[2][256][64];   // 64 KB
  __shared__ unsigned short Bs[2][256][64];   // 64 KB
  const int tid = threadIdx.x;

  // ---- block swizzle: XCD-chunked (nwg%8==0) + GM=4 row grouping ----
  int nwg = gridDim.x;
  int id  = blockIdx.x;
  id = (id & 7) * (nwg >> 3) + (id >> 3);
  int gsz = nx << 2;
  int g = id / gsz, rem = id % gsz;
  const int bm = ((g << 2) + (rem & 3)) * 256;
  const int bn = (rem >> 2) * 256;

  const int lane = tid & 63, wid = tid >> 6;
  const int wr = wid >> 2, wc = wid & 3;        // wave tile: rows wr*128, cols wc*64
  const int l31 = lane & 31, khalf = lane >> 5; // 32x32 operand coords

  // staging lane map: wave stripe = 8 rows x 128 B; lane l -> row +=(l>>3), lin slot l&7.
  const int srow  = lane >> 3;                  // row within 8-row stripe
  const int gslot = (lane & 7) ^ srow;          // pre-swizzled global 16B-slot

  auto stageA13 = [&](int bf, int kt){          // A-P1: sweeps 1,3
    const size_t ko = (size_t)kt * 64 + gslot * 8;
    gll16(A + (size_t)(bm +  64 + wid*8 + srow) * K + ko, &As[bf][ 64 + wid*8][0]);
    gll16(A + (size_t)(bm + 192 + wid*8 + srow) * K + ko, &As[bf][192 + wid*8][0]);
  };
  auto stageA02 = [&](int bf, int kt){          // A-P0: sweeps 0,2
    const size_t ko = (size_t)kt * 64 + gslot * 8;
    gll16(A + (size_t)(bm +       wid*8 + srow) * K + ko, &As[bf][      wid*8][0]);
    gll16(A + (size_t)(bm + 128 + wid*8 + srow) * K + ko, &As[bf][128 + wid*8][0]);
  };
  auto stageB4 = [&](int bf, int kt){           // B: sweeps 0..3
    const size_t ko = (size_t)kt * 64 + gslot * 8;
    #pragma unroll
    for (int s = 0; s < 4; s++)
      gll16(Bt + (size_t)(bn + s*64 + wid*8 + srow) * K + ko, &Bs[bf][s*64 + wid*8][0]);
  };

  // frag reads (32x32x16): row = base + l31; logical slot q = kk*2 + khalf; lin = q^(row&7)
  auto lda = [&](int bf, int mf, int kk) -> short8 {
    return *(const short8*)&As[bf][wr*128 + mf*32 + l31][(((kk<<1)+khalf) ^ (l31&7)) << 3];
  };
  auto ldb = [&](int bf, int nf, int kk) -> short8 {
    return *(const short8*)&Bs[bf][wc*64 + nf*32 + l31][(((kk<<1)+khalf) ^ (l31&7)) << 3];
  };

  f32x16 acc[4][2];
  #pragma unroll
  for (int i = 0; i < 4; i++)
    #pragma unroll
    for (int j = 0; j < 2; j++)
      #pragma unroll
      for (int e = 0; e < 16; e++)
        acc[i][j][e] = 0.f;

  const int NT = K >> 6;
  // prologue: A-P0(0)+B(0) [6] | A-P1(0) [2] | A-P0(1)+B(1) [6] -> 14 out, force oldest 6
  stageA02(0, 0); stageB4(0, 0);
  stageA13(0, 0);
  stageA02(1, 1); stageB4(1, 1);
  asm volatile("s_waitcnt vmcnt(8)" ::: "memory");
  __builtin_amdgcn_s_barrier();

  for (int kt = 0; kt < NT; ++kt){
    const int bf = kt & 1, nbf = bf ^ 1;
    const int k1 = (kt+1 < NT) ? kt+1 : kt;   // tail: dummy re-stage into dead regions
    const int k2 = (kt+2 < NT) ? kt+2 : kt;
    // ---- phase 1: all B frags + A mf0-1 (P0 rows) ----
    short8 bfr[4][2];
    #pragma unroll
    for (int kk = 0; kk < 4; kk++)
      #pragma unroll
      for (int nf = 0; nf < 2; nf++)
        bfr[kk][nf] = ldb(bf, nf, kk);
    short8 af0[4][2];
    #pragma unroll
    for (int kk = 0; kk < 4; kk++)
      #pragma unroll
      for (int mf = 0; mf < 2; mf++)
        af0[kk][mf] = lda(bf, mf, kk);
    stageA13(nbf, k1);
    __builtin_amdgcn_s_setprio(1);
    #pragma unroll
    for (int mf = 0; mf < 2; mf++)
      #pragma unroll
      for (int kk = 0; kk < 4; kk++)
        #pragma unroll
        for (int nf = 0; nf < 2; nf++)
          acc[mf][nf] = __builtin_amdgcn_mfma_f32_32x32x16_bf16(af0[kk][mf], bfr[kk][nf], acc[mf][nf], 0, 0, 0);
    __builtin_amdgcn_s_setprio(0);
    asm volatile("s_waitcnt vmcnt(8) lgkmcnt(0)" ::: "memory");  // forces A-P1(kt); my reads retired
    __builtin_amdgcn_s_barrier();
    // ---- phase 2: A mf2-3 (P1 rows); stage kt+2 into regions dead after phase 1 ----
    short8 af1[4][2];
    #pragma unroll
    for (int kk = 0; kk < 4; kk++)
      #pragma unroll
      for (int mf = 0; mf < 2; mf++)
        af1[kk][mf] = lda(bf, 2+mf, kk);
    stageA02(bf, k2);
    stageB4(bf, k2);
    __builtin_amdgcn_s_setprio(1);
    #pragma unroll
    for (int mf = 0; mf < 2; mf++)
      #pragma unroll
      for (int kk = 0; kk < 4; kk++)
        #pragma unroll
        for (int nf = 0; nf < 2; nf++)
          acc[2+mf][nf] = __builtin_amdgcn_mfma_f32_32x32x16_bf16(af1[kk][mf], bfr[kk][nf], acc[2+mf][nf], 0, 0, 0);
    __builtin_amdgcn_s_setprio(0);
    asm volatile("s_waitcnt vmcnt(8) lgkmcnt(0)" ::: "memory");  // forces A-P0(kt+1)+B(kt+1)
    __builtin_amdgcn_s_barrier();
  }
  asm volatile("s_waitcnt vmcnt(0)" ::: "memory");   // drain tail dummy stages

  // epilogue: C/D 32x32 layout: col = lane&31, row = (reg&3) + 8*(reg>>2) + 4*(lane>>5)
  const int rquad = khalf * 4;
  #pragma unroll
  for (int mf = 0; mf < 4; mf++){
    #pragma unroll
    for (int nf = 0; nf < 2; nf++){
      #pragma unroll
      for (int reg = 0; reg < 16; reg++){
        int m = bm + wr*128 + mf*32 + (reg & 3) + 8*(reg >> 2) + rquad;
        int n = bn + wc*64 + nf*32 + l31;
        float vv = acc[mf][nf][reg];
        if (EPI == EPI_RKV3){
          // n in [0,3072): 0->rT, 1024->kT, 2048->vT (contiguous); [B,H,T,S] layout
          unsigned short* o = (unsigned short*)outp;
          int b = m >> 11, t = m & (T_ - 1);
          int which = n >> 10, h = (n >> 6) & (H_ - 1), s = n & (S_ - 1);
          o[(size_t)which * BT_ * C_ + (((size_t)(b * H_ + h)) * T_ + t) * S_ + s] = f2bf(vv);
        } else if (EPI == EPI_WO){
          float* o = (float*)outp;
          o[(size_t)m * C_ + n] = aux[(size_t)m * C_ + n] + vv;   // residual add
        } else if (EPI == EPI_FK){
          unsigned short* o = (unsigned short*)outp;
          float rl = vv > 0.f ? vv : 0.f;
          o[(size_t)m * FF_ + n] = f2bf(rl * rl);                 // relu^2
        } else { // EPI_FV
          float* o = (float*)outp;
          o[(size_t)m * C_ + n] += vv;                            // accumulate into residual
        }
      }
    }
  }
}

// ================= WKV6 chunked (L=64) =================
// AS buffer (bf16, [bh][c][v][k], reuses xln region):
//   after P1: A_c[v][k] = sum_t V[t][v] k[t][k] d[k]^{63-t}
//   after P2 (in-place): S_c[v][k] = state at START of chunk c

// P1: per (bh, chunk) outer-product accumulation via MFMA
__global__ __launch_bounds__(256) void wkv_p1(
    const unsigned short* __restrict__ kT, const unsigned short* __restrict__ vT,
    const float* __restrict__ td, unsigned short* __restrict__ AS){
  const int bid = blockIdx.x;
  const int bh = bid >> 5, c = bid & (NC_ - 1);
  const int h = bh & (H_ - 1);
  const int tid = threadIdx.x, lane = tid & 63, w = tid >> 6;
  __shared__ unsigned short kh[64][72];   // k-hat [k][t]
  __shared__ unsigned short vt[64][72];   // V^T   [v][t]
  __shared__ float eps[64];
  if (tid < 64) eps[tid] = expf(td[h * S_ + tid]);
  __syncthreads();
  const int t = tid >> 2, q = (tid & 3) * 16;
  const size_t base = ((size_t)bh * T_ + c * 64 + t) * S_ + q;
  U8 k0, k1, v0, v1;
  k0.v = *(const uint4*)(kT + base);  k1.v = *(const uint4*)(kT + base + 8);
  v0.v = *(const uint4*)(vT + base);  v1.v = *(const uint4*)(vT + base + 8);
  const float mt = -(float)(63 - t);
  #pragma unroll
  for (int j = 0; j < 8; j++){
    int k = q + j;
    kh[k][t] = f2bf(bf2f(k0.s[j]) * expf(mt * eps[k]));
    vt[k][t] = v0.s[j];
  }
  #pragma unroll
  for (int j = 0; j < 8; j++){
    int k = q + 8 + j;
    kh[k][t] = f2bf(bf2f(k1.s[j]) * expf(mt * eps[k]));
    vt[k][t] = v1.s[j];
  }
  __syncthreads();
  const int ml = lane & 15, klo = (lane >> 4) * 8;
  f32x4 acc[4];
  #pragma unroll
  for (int nf = 0; nf < 4; nf++) acc[nf] = (f32x4){0.f,0.f,0.f,0.f};
  #pragma unroll
  for (int ks = 0; ks < 2; ks++){
    short8 af = *(const short8*)&vt[w*16 + ml][ks*32 + klo];
    #pragma unroll
    for (int nf = 0; nf < 4; nf++){
      short8 bfr = *(const short8*)&kh[nf*16 + ml][ks*32 + klo];
      acc[nf] = __builtin_amdgcn_mfma_f32_16x16x32_bf16(af, bfr, acc[nf], 0, 0, 0);
    }
  }
  unsigned short* dst = AS + ((size_t)bid * 64 + w*16 + (lane >> 4) * 4) * 64;
  #pragma unroll
  for (int nf = 0; nf < 4; nf++)
    #pragma unroll
    for (int r = 0; r < 4; r++)
      dst[(size_t)r * 64 + nf*16 + ml] = f2bf(acc[nf][r]);
}

// P2: chain boundary states IN PLACE: read A_c (bf16), write S_c (bf16) over it.
__global__ __launch_bounds__(256) void wkv_p2(
    unsigned short* __restrict__ AS, const float* __restrict__ td){
  const int bh = blockIdx.x >> 2, vs = blockIdx.x & 3;
  const int h = bh & (H_ - 1);
  const int tid = threadIdx.x;
  const int vo = tid >> 4, k4 = (tid & 15) * 4;
  const int v = vs * 16 + vo;
  float dL[4], S[4];
  #pragma unroll
  for (int j = 0; j < 4; j++){
    dL[j] = expf(-64.f * expf(td[h * S_ + k4 + j]));
    S[j] = 0.f;
  }
  const size_t rb = ((size_t)bh * NC_ * 64 + v) * 64 + k4;
  for (int c = 0; c < NC_; c++){
    unsigned short* p = AS + rb + (size_t)c * 4096;
    ushort4 A = *(const ushort4*)p;          // read A_c
    ushort4 o;
    o.x = f2bf(S[0]); o.y = f2bf(S[1]); o.z = f2bf(S[2]); o.w = f2bf(S[3]);
    *(ushort4*)p = o;                        // overwrite with S_c
    S[0] = fmaf(S[0], dL[0], bf2f(A.x)); S[1] = fmaf(S[1], dL[1], bf2f(A.y));
    S[2] = fmaf(S[2], dL[2], bf2f(A.z)); S[3] = fmaf(S[3], dL[3], bf2f(A.w));
  }
}

// P3: per (bh, chunk): Y = (tril(Rt Kt^T) + diag(u-term)) V + Rt S_c ; gate; emit rwkv
__global__ __launch_bounds__(256) void wkv_p3(
    const unsigned short* __restrict__ rT, const unsigned short* __restrict__ kT,
    const unsigned short* __restrict__ vT, const unsigned short* __restrict__ Sb,
    const float* __restrict__ td, const float* __restrict__ tf,
    unsigned short* __restrict__ rwkv){
  const int bid = blockIdx.x;
  const int bh = bid >> 5, c = bid & (NC_ - 1);
  const int b = bh >> 4, h = bh & (H_ - 1);
  const int tid = threadIdx.x, lane = tid & 63, w = tid >> 6;
  __shared__ unsigned short Rt[64][72];   // r * d^t        [t][k]
  __shared__ unsigned short Kt[64][72];   // k * d^{-(t+1)} [i][k] -> reused as A[t][i]
  __shared__ unsigned short Vt[64][72];   // V^T [v][t]
  __shared__ unsigned short Sc[64][72];   // S_c [v][k]
  __shared__ float eps[64], us[64], diag[64];
  __shared__ float dred[64][4];

  if (tid < 64){ eps[tid] = expf(td[h * S_ + tid]); us[tid] = tf[h * S_ + tid]; }
  __syncthreads();

  const int t = tid >> 2, q = (tid & 3) * 16;
  const size_t base  = ((size_t)bh * T_ + c * 64 + t) * S_ + q;
  const size_t sbase = (((size_t)bh * NC_ + c) * 64 + t) * 64 + q;
  {
    U8 r0, r1, k0, k1, v0, v1, s0, s1, rt0, rt1, kt0, kt1;
    r0.v = *(const uint4*)(rT + base);  r1.v = *(const uint4*)(rT + base + 8);
    k0.v = *(const uint4*)(kT + base);  k1.v = *(const uint4*)(kT + base + 8);
    v0.v = *(const uint4*)(vT + base);  v1.v = *(const uint4*)(vT + base + 8);
    s0.v = *(const uint4*)(Sb + sbase); s1.v = *(const uint4*)(Sb + sbase + 8);
    float dpart = 0.f;
    const float ft = (float)t;
    #pragma unroll
    for (int j = 0; j < 8; j++){
      int k = q + j;
      float ep = eps[k];
      float rv = bf2f(r0.s[j]), kv = bf2f(k0.s[j]);
      rt0.s[j] = f2bf(rv * expf(-ft * ep));
      kt0.s[j] = f2bf(kv * expf((ft + 1.f) * ep));
      dpart = fmaf(rv * us[k], kv, dpart);
      Vt[k][t] = v0.s[j];
    }
    #pragma unroll
    for (int j = 0; j < 8; j++){
      int k = q + 8 + j;
      float ep = eps[k];
      float rv = bf2f(r1.s[j]), kv = bf2f(k1.s[j]);
      rt1.s[j] = f2bf(rv * expf(-ft * ep));
      kt1.s[j] = f2bf(kv * expf((ft + 1.f) * ep));
      dpart = fmaf(rv * us[k], kv, dpart);
      Vt[k][t] = v1.s[j];
    }
    *(uint4*)&Rt[t][q]     = rt0.v;  *(uint4*)&Rt[t][q + 8] = rt1.v;
    *(uint4*)&Kt[t][q]     = kt0.v;  *(uint4*)&Kt[t][q + 8] = kt1.v;
    *(uint4*)&Sc[t][q]     = s0.v;   *(uint4*)&Sc[t][q + 8] = s1.v;
    dred[t][tid & 3] = dpart;
  }
  __syncthreads();
  if (tid < 64) diag[tid] = dred[tid][0] + dred[tid][1] + dred[tid][2] + dred[tid][3];

  const int ml = lane & 15, klo = (lane >> 4) * 8;
  // GEMM1: scores E[t][i]
  f32x4 acc1[4];
  #pragma unroll
  for (int nf = 0; nf < 4; nf++) acc1[nf] = (f32x4){0.f,0.f,0.f,0.f};
  #pragma unroll
  for (int ks = 0; ks < 2; ks++){
    short8 af = *(const short8*)&Rt[w*16 + ml][ks*32 + klo];
    #pragma unroll
    for (int nf = 0; nf < 4; nf++){
      short8 bfr = *(const short8*)&Kt[nf*16 + ml][ks*32 + klo];
      acc1[nf] = __builtin_amdgcn_mfma_f32_16x16x32_bf16(af, bfr, acc1[nf], 0, 0, 0);
    }
  }
  __syncthreads();   // GEMM1 reads done; diag visible

  // mask + u-diagonal, convert to bf16, store A into Kt space
  #pragma unroll
  for (int nf = 0; nf < 4; nf++){
    #pragma unroll
    for (int r = 0; r < 4; r++){
      int tt = w*16 + (lane >> 4) * 4 + r;
      int ii = nf*16 + ml;
      float e = acc1[nf][r];
      float val = (ii < tt) ? e : (ii == tt ? diag[tt] : 0.f);
      Kt[tt][ii] = f2bf(val);
    }
  }
  __syncthreads();

  // GEMM2: Y = A V + Rt S_c
  f32x4 acc2[4];
  #pragma unroll
  for (int nf = 0; nf < 4; nf++) acc2[nf] = (f32x4){0.f,0.f,0.f,0.f};
  #pragma unroll
  for (int ks = 0; ks < 2; ks++){
    short8 aA = *(const short8*)&Kt[w*16 + ml][ks*32 + klo];
    short8 aR = *(const short8*)&Rt[w*16 + ml][ks*32 + klo];
    #pragma unroll
    for (int nf = 0; nf < 4; nf++){
      short8 bV = *(const short8*)&Vt[nf*16 + ml][ks*32 + klo];
      acc2[nf] = __builtin_amdgcn_mfma_f32_16x16x32_bf16(aA, bV, acc2[nf], 0, 0, 0);
      short8 bS = *(const short8*)&Sc[nf*16 + ml][ks*32 + klo];
      acc2[nf] = __builtin_amdgcn_mfma_f32_16x16x32_bf16(aR, bS, acc2[nf], 0, 0, 0);
    }
  }

  // epilogue: gate with sigmoid(raw r), emit rwkv [B,T,C] bf16
  const size_t rrow = ((size_t)bh * T_ + c * 64) * S_;
  #pragma unroll
  for (int nf = 0; nf < 4; nf++){
    #pragma unroll
    for (int r = 0; r < 4; r++){
      int tt = w*16 + (lane >> 4) * 4 + r;
      int vv = nf*16 + ml;
      float y = acc2[nf][r];
      float rv = bf2f(rT[rrow + (size_t)tt * S_ + vv]);
      float sig = 1.f / (1.f + expf(-rv));
      rwkv[((size_t)b * T_ + c * 64 + tt) * C_ + h * S_ + vv] = f2bf(sig * y);
    }
  }
}

// ---------------- host ----------------
extern "C" void kernel_launch(void* const* d_in, const int* in_sizes, int n_in,
                              void* d_out, int out_size, void* d_ws, size_t ws_size,
                              hipStream_t stream){
  const float* x    = (const float*)d_in[0];
  const float* td   = (const float*)d_in[1];
  const float* tf   = (const float*)d_in[2];
  const float* w_r  = (const float*)d_in[3];
  const float* w_k  = (const float*)d_in[4];
  const float* w_v  = (const float*)d_in[5];
  const float* w_o  = (const float*)d_in[6];
  const float* w_fk = (const float*)d_in[7];
  const float* w_fv = (const float*)d_in[8];
  const float* g1   = (const float*)d_in[9];
  const float* b1   = (const float*)d_in[10];
  const float* g2   = (const float*)d_in[11];
  const float* b2   = (const float*)d_in[12];
  float* out = (float*)d_out;

  char* ws = (char*)d_ws;
  size_t off = 0;
  auto alloc = [&](size_t bytes){ char* p = ws + off; off += (bytes + 255) & ~(size_t)255; return p; };
  unsigned short* wrT  = (unsigned short*)alloc((size_t)C_ * C_ * 2);  // wrT,wkT,wvT contiguous -> [3072][1024]
  unsigned short* wkT  = (unsigned short*)alloc((size_t)C_ * C_ * 2);
  unsigned short* wvT  = (unsigned short*)alloc((size_t)C_ * C_ * 2);
  unsigned short* woT  = (unsigned short*)alloc((size_t)C_ * C_ * 2);
  unsigned short* wfkT = (unsigned short*)alloc((size_t)C_ * FF_ * 2);
  unsigned short* wfvT = (unsigned short*)alloc((size_t)FF_ * C_ * 2);
  unsigned short* xln  = (unsigned short*)alloc((size_t)BT_ * C_ * 2);
  unsigned short* rT   = (unsigned short*)alloc((size_t)BT_ * C_ * 2); // rT,kT,vT contiguous
  unsigned short* kT   = (unsigned short*)alloc((size_t)BT_ * C_ * 2);
  unsigned short* vT   = (unsigned short*)alloc((size_t)BT_ * C_ * 2);
  unsigned short* rwkv = (unsigned short*)alloc((size_t)BT_ * C_ * 2);
  unsigned short* hbuf = rT;   // FFN hidden reuses rT..rwkv (134MB) after scan
  unsigned short* AS   = xln;  // chunk A/S buffer reuses xln (exactly BT_*C_ bf16)

  dim3 blk(256);
  dim3 blk5(512);

  // merged weight conversions (transpose to [N][K] bf16): one launch
  wconv6_kernel<<<dim3(12288), blk, 0, stream>>>(w_r, w_k, w_v, w_o, w_fk, w_fv,
                                                 wrT, wkT, wvT, woT, wfkT, wfvT);

  // LN1
  ln_kernel<<<BT_, blk, 0, stream>>>(x, g1, b1, xln);

  // fused r|k|v projection: N=3072 -> transposed [B,H,T,S] bf16 x3
  gemm64_kernel<EPI_RKV3><<<dim3((3*C_/256)*(BT_/256)), blk5, 0, stream>>>(xln, wrT, rT, nullptr, C_, 3*C_/256);

  // WKV6 chunked scan (A/S in xln region, in-place chain)
  wkv_p1<<<B_*H_*NC_, blk, 0, stream>>>(kT, vT, td, AS);
  wkv_p2<<<B_*H_*4,   blk, 0, stream>>>(AS, td);
  wkv_p3<<<B_*H_*NC_, blk, 0, stream>>>(rT, kT, vT, AS, td, tf, rwkv);

  // output projection + residual -> d_out (fp32)
  gemm64_kernel<EPI_WO><<<dim3((C_/256)*(BT_/256)), blk5, 0, stream>>>(rwkv, woT, out, x, C_, C_/256);

  // LN2
  ln_kernel<<<BT_, blk, 0, stream>>>(out, g2, b2, xln);

  // FFN
  gemm64_kernel<EPI_FK><<<dim3((FF_/256)*(BT_/256)), blk5, 0, stream>>>(xln, wfkT, hbuf, nullptr, C_, FF_/256);
  gemm64_kernel<EPI_FV><<<dim3((C_/256)*(BT_/256)), blk5, 0, stream>>>(hbuf, wfvT, out, nullptr, FF_, C_/256);
}

// Round 14
// 548.370 us; speedup vs baseline: 1.0665x; 1.0665x over previous
//
#include <hip/hip_runtime.h>
#include <hip/hip_bf16.h>

#define B_ 8
#define T_ 2048
#define C_ 1024
#define H_ 16
#define S_ 64
#define BT_ (B_*T_)   // 16384
#define FF_ (4*C_)    // 4096
#define NC_ 32        // chunks per sequence (T/64)

typedef __attribute__((ext_vector_type(8))) short short8;
typedef __attribute__((ext_vector_type(4))) float f32x4;

union U8 { uint4 v; unsigned short s[8]; };

static __device__ __forceinline__ unsigned short f2bf(float f){
  unsigned u = __float_as_uint(f);
  unsigned r = (u + 0x7fffu + ((u >> 16) & 1u)) >> 16;
  return (unsigned short)r;
}
static __device__ __forceinline__ float bf2f(unsigned short u){
  return __uint_as_float(((unsigned)u) << 16);
}

// async global->LDS, 16B per lane; LDS dest = wave-uniform base + lane*16
static __device__ __forceinline__ void gll16(const unsigned short* g, unsigned short* l){
  __builtin_amdgcn_global_load_lds((const __attribute__((address_space(1))) void*)g,
                                   (__attribute__((address_space(3))) void*)l, 16, 0, 0);
}

// ---------------- LayerNorm: fp32 in -> bf16 out ----------------
__global__ __launch_bounds__(256) void ln_kernel(const float* __restrict__ x,
    const float* __restrict__ g, const float* __restrict__ b,
    unsigned short* __restrict__ out){
  int row = blockIdx.x;
  int tid = threadIdx.x;
  const float4* xr = reinterpret_cast<const float4*>(x + (size_t)row * C_);
  float4 v = xr[tid];
  float s = v.x + v.y + v.z + v.w;
  float q = v.x*v.x + v.y*v.y + v.z*v.z + v.w*v.w;
  int lane = tid & 63, w = tid >> 6;
  #pragma unroll
  for (int off = 32; off; off >>= 1){ s += __shfl_down(s, off); q += __shfl_down(q, off); }
  __shared__ float red[2][4];
  if (lane == 0){ red[0][w] = s; red[1][w] = q; }
  __syncthreads();
  s = red[0][0] + red[0][1] + red[0][2] + red[0][3];
  q = red[1][0] + red[1][1] + red[1][2] + red[1][3];
  float mean = s * (1.0f / C_);
  float var  = q * (1.0f / C_) - mean * mean;
  float inv = rsqrtf(var + 1e-5f);
  float4 gg = reinterpret_cast<const float4*>(g)[tid];
  float4 bb = reinterpret_cast<const float4*>(b)[tid];
  ushort4 o;
  o.x = f2bf((v.x - mean) * inv * gg.x + bb.x);
  o.y = f2bf((v.y - mean) * inv * gg.y + bb.y);
  o.z = f2bf((v.z - mean) * inv * gg.z + bb.z);
  o.w = f2bf((v.w - mean) * inv * gg.w + bb.w);
  reinterpret_cast<ushort4*>(out + (size_t)row * C_)[tid] = o;
}

// ---------------- merged weight convert+transpose: 6 weights, one launch ----------------
// blocks [0,4096): w_r/w_k/w_v/w_o (1024x1024 each); [4096,8192): w_fk (1024x4096);
// [8192,12288): w_fv (4096x1024). w[K][N] f32 -> wt[N][K] bf16.
__global__ __launch_bounds__(256) void wconv6_kernel(
    const float* __restrict__ w0, const float* __restrict__ w1,
    const float* __restrict__ w2, const float* __restrict__ w3,
    const float* __restrict__ w4, const float* __restrict__ w5,
    unsigned short* __restrict__ d0, unsigned short* __restrict__ d1,
    unsigned short* __restrict__ d2, unsigned short* __restrict__ d3,
    unsigned short* __restrict__ d4, unsigned short* __restrict__ d5){
  __shared__ float tile[32][33];
  const int idx = blockIdx.x;
  const float* w; unsigned short* wt; int K, N, bk, bn;
  if (idx < 4096){
    int which = idx >> 10, i = idx & 1023;
    w  = which==0 ? w0 : which==1 ? w1 : which==2 ? w2 : w3;
    wt = which==0 ? d0 : which==1 ? d1 : which==2 ? d2 : d3;
    K = 1024; N = 1024;
    bk = (i & 31) * 32; bn = (i >> 5) * 32;
  } else if (idx < 8192){
    int i = idx - 4096;
    w = w4; wt = d4; K = 1024; N = 4096;
    bk = (i & 31) * 32; bn = (i >> 5) * 32;
  } else {
    int i = idx - 8192;
    w = w5; wt = d5; K = 4096; N = 1024;
    bk = (i & 127) * 32; bn = (i >> 7) * 32;
  }
  int tx = threadIdx.x & 31, ty = threadIdx.x >> 5; // ty 0..7
  #pragma unroll
  for (int i = 0; i < 4; i++)
    tile[ty + 8*i][tx] = w[(size_t)(bk + ty + 8*i) * N + bn + tx];
  __syncthreads();
  #pragma unroll
  for (int i = 0; i < 4; i++)
    wt[(size_t)(bn + ty + 8*i) * K + bk + tx] = f2bf(tile[tx][ty + 8*i]);
}

// ---------------- 256x256 bf16 MFMA GEMM, BK=64, 2-phase counted-vmcnt pipeline ----------------
// (round-10/12 proven best: ~144 us/dispatch, MfmaUtil 41%, bank-conflict 0, no spill)
// out = A[M,K] @ Bt[N,K]^T. 512 threads = 8 waves (2M x 4N), per-wave C = 128x64.
// 16x16x32 fragments. LDS: 2 buf x [256][64] x 2 operands = 128 KB -> 1 block/CU.
// Swizzle: rows are 128 B (= bank period); 16B-slot s at row r stored at s ^ (r&7)
//   (pre-swizzled gll SOURCE + same XOR on frag reads) -> conflict-free in 8-row stripes.
// Shape note: 32x32x16 frags measured SLOWER (round 13: 4-way frag-read conflict —
//   row span 32 makes slot q^(row&7) alias every 8 lanes). Keep 16x16x32.
// Tile note: 128^2 @ 2 blocks/CU measured slower (round 11). Keep 256^2.
// Ledger (per wave, gll counts 1 each; A-P0={rows 0-63,128-191}, A-P1={64-127,192-255}):
//   ph1 of kt: read all B + A-P0 from buf bf; issue A-P1(kt+1)->nbf [2];
//              MFMA 32; vmcnt(8) forces A-P1(kt); lgkm(0); barrier.
//   ph2 of kt: read A-P1 from bf; issue A-P0(kt+2)+B(kt+2)->bf [6] (dead regions);
//              MFMA 32; vmcnt(8) forces A-P0(kt+1)+B(kt+1); lgkm(0); barrier.
// __launch_bounds__(512,2): <=256 VGPR, no spill (round-8 lesson).
#define EPI_RKV3 1
#define EPI_WO   2
#define EPI_FK   3
#define EPI_FV   4

template<int EPI>
__global__ __launch_bounds__(512, 2) void gemm64_kernel(
    const unsigned short* __restrict__ A,   // [M,K] bf16 row-major
    const unsigned short* __restrict__ Bt,  // [N,K] bf16 row-major
    void* __restrict__ outp,
    const float* __restrict__ aux,
    int K, int nx){
  __shared__ unsigned short As[2][256][64];   // 64 KB
  __shared__ unsigned short Bs[2][256][64];   // 64 KB
  const int tid = threadIdx.x;

  // ---- block swizzle: XCD-chunked (nwg%8==0) + GM=4 row grouping ----
  int nwg = gridDim.x;
  int id  = blockIdx.x;
  id = (id & 7) * (nwg >> 3) + (id >> 3);
  int gsz = nx << 2;
  int g = id / gsz, rem = id % gsz;
  const int bm = ((g << 2) + (rem & 3)) * 256;
  const int bn = (rem >> 2) * 256;

  const int lane = tid & 63, wid = tid >> 6;
  const int wr = wid >> 2, wc = wid & 3;        // wave tile: rows wr*128, cols wc*64
  const int ml = lane & 15, hi = lane >> 4;

  // staging lane map: wave stripe = 8 rows x 128 B; lane l -> row +=(l>>3), lin slot l&7.
  // linear slot sl at row r holds global slot sl ^ (r&7); r&7 == l>>3 here.
  const int srow  = lane >> 3;                  // row within 8-row stripe
  const int gslot = (lane & 7) ^ srow;          // pre-swizzled global 16B-slot

  // sweep s covers rows s*64..s*64+63; wave wid owns rows s*64 + wid*8 .. +7
  auto stageA13 = [&](int bf, int kt){          // A-P1: sweeps 1,3
    const size_t ko = (size_t)kt * 64 + gslot * 8;
    gll16(A + (size_t)(bm +  64 + wid*8 + srow) * K + ko, &As[bf][ 64 + wid*8][0]);
    gll16(A + (size_t)(bm + 192 + wid*8 + srow) * K + ko, &As[bf][192 + wid*8][0]);
  };
  auto stageA02 = [&](int bf, int kt){          // A-P0: sweeps 0,2
    const size_t ko = (size_t)kt * 64 + gslot * 8;
    gll16(A + (size_t)(bm +       wid*8 + srow) * K + ko, &As[bf][      wid*8][0]);
    gll16(A + (size_t)(bm + 128 + wid*8 + srow) * K + ko, &As[bf][128 + wid*8][0]);
  };
  auto stageB4 = [&](int bf, int kt){           // B: sweeps 0..3
    const size_t ko = (size_t)kt * 64 + gslot * 8;
    #pragma unroll
    for (int s = 0; s < 4; s++)
      gll16(Bt + (size_t)(bn + s*64 + wid*8 + srow) * K + ko, &Bs[bf][s*64 + wid*8][0]);
  };

  // frag reads: row = base + ml, logical slot q = kk*4 + hi, lin slot = q ^ (ml&7)
  auto lda = [&](int bf, int mf, int kk) -> short8 {
    return *(const short8*)&As[bf][wr*128 + mf*16 + ml][(((kk<<2)+hi) ^ (ml&7)) << 3];
  };
  auto ldb = [&](int bf, int nf, int kk) -> short8 {
    return *(const short8*)&Bs[bf][wc*64 + nf*16 + ml][(((kk<<2)+hi) ^ (ml&7)) << 3];
  };

  f32x4 acc[8][4];
  #pragma unroll
  for (int i = 0; i < 8; i++)
    #pragma unroll
    for (int j = 0; j < 4; j++)
      acc[i][j] = (f32x4){0.f, 0.f, 0.f, 0.f};

  const int NT = K >> 6;
  // prologue: A-P0(0)+B(0) [6] | A-P1(0) [2] | A-P0(1)+B(1) [6] -> 14 out, force oldest 6
  stageA02(0, 0); stageB4(0, 0);
  stageA13(0, 0);
  stageA02(1, 1); stageB4(1, 1);
  asm volatile("s_waitcnt vmcnt(8)" ::: "memory");
  __builtin_amdgcn_s_barrier();

  for (int kt = 0; kt < NT; ++kt){
    const int bf = kt & 1, nbf = bf ^ 1;
    const int k1 = (kt+1 < NT) ? kt+1 : kt;   // tail: dummy re-stage into dead regions
    const int k2 = (kt+2 < NT) ? kt+2 : kt;
    // ---- phase 1: all B frags + A-P0 (mf0-3) ----
    short8 bfr[2][4];
    #pragma unroll
    for (int kk = 0; kk < 2; kk++)
      #pragma unroll
      for (int nf = 0; nf < 4; nf++)
        bfr[kk][nf] = ldb(bf, nf, kk);
    short8 af0[2][4];
    #pragma unroll
    for (int kk = 0; kk < 2; kk++)
      #pragma unroll
      for (int mf = 0; mf < 4; mf++)
        af0[kk][mf] = lda(bf, mf, kk);
    stageA13(nbf, k1);
    __builtin_amdgcn_s_setprio(1);
    #pragma unroll
    for (int mf = 0; mf < 4; mf++)
      #pragma unroll
      for (int kk = 0; kk < 2; kk++)
        #pragma unroll
        for (int nf = 0; nf < 4; nf++)
          acc[mf][nf] = __builtin_amdgcn_mfma_f32_16x16x32_bf16(af0[kk][mf], bfr[kk][nf], acc[mf][nf], 0, 0, 0);
    __builtin_amdgcn_s_setprio(0);
    asm volatile("s_waitcnt vmcnt(8) lgkmcnt(0)" ::: "memory");  // forces A-P1(kt); my reads retired
    __builtin_amdgcn_s_barrier();
    // ---- phase 2: A-P1 (mf4-7); stage kt+2 into regions dead after phase 1 ----
    short8 af1[2][4];
    #pragma unroll
    for (int kk = 0; kk < 2; kk++)
      #pragma unroll
      for (int mf = 0; mf < 4; mf++)
        af1[kk][mf] = lda(bf, 4+mf, kk);
    stageA02(bf, k2);
    stageB4(bf, k2);
    __builtin_amdgcn_s_setprio(1);
    #pragma unroll
    for (int mf = 0; mf < 4; mf++)
      #pragma unroll
      for (int kk = 0; kk < 2; kk++)
        #pragma unroll
        for (int nf = 0; nf < 4; nf++)
          acc[4+mf][nf] = __builtin_amdgcn_mfma_f32_16x16x32_bf16(af1[kk][mf], bfr[kk][nf], acc[4+mf][nf], 0, 0, 0);
    __builtin_amdgcn_s_setprio(0);
    asm volatile("s_waitcnt vmcnt(8) lgkmcnt(0)" ::: "memory");  // forces A-P0(kt+1)+B(kt+1)
    __builtin_amdgcn_s_barrier();
  }
  asm volatile("s_waitcnt vmcnt(0)" ::: "memory");   // drain tail dummy stages

  // epilogue
  const int rbase = bm + wr*128 + hi*4;
  const int cbase = bn + wc*64 + ml;
  #pragma unroll
  for (int mf = 0; mf < 8; mf++){
    #pragma unroll
    for (int nf = 0; nf < 4; nf++){
      #pragma unroll
      for (int r = 0; r < 4; r++){
        int m = rbase + mf*16 + r;
        int n = cbase + nf*16;
        float vv = acc[mf][nf][r];
        if (EPI == EPI_RKV3){
          // n in [0,3072): 0->rT, 1024->kT, 2048->vT (contiguous); [B,H,T,S] layout
          unsigned short* o = (unsigned short*)outp;
          int b = m >> 11, t = m & (T_ - 1);
          int which = n >> 10, h = (n >> 6) & (H_ - 1), s = n & (S_ - 1);
          o[(size_t)which * BT_ * C_ + (((size_t)(b * H_ + h)) * T_ + t) * S_ + s] = f2bf(vv);
        } else if (EPI == EPI_WO){
          float* o = (float*)outp;
          o[(size_t)m * C_ + n] = aux[(size_t)m * C_ + n] + vv;   // residual add
        } else if (EPI == EPI_FK){
          unsigned short* o = (unsigned short*)outp;
          float rl = vv > 0.f ? vv : 0.f;
          o[(size_t)m * FF_ + n] = f2bf(rl * rl);                 // relu^2
        } else { // EPI_FV
          float* o = (float*)outp;
          o[(size_t)m * C_ + n] += vv;                            // accumulate into residual
        }
      }
    }
  }
}

// ================= WKV6 chunked (L=64) =================
// AS buffer (bf16, [bh][c][v][k], reuses xln region):
//   after P1: A_c[v][k] = sum_t V[t][v] k[t][k] d[k]^{63-t}
//   after P2 (in-place): S_c[v][k] = state at START of chunk c

// P1: per (bh, chunk) outer-product accumulation via MFMA
__global__ __launch_bounds__(256) void wkv_p1(
    const unsigned short* __restrict__ kT, const unsigned short* __restrict__ vT,
    const float* __restrict__ td, unsigned short* __restrict__ AS){
  const int bid = blockIdx.x;
  const int bh = bid >> 5, c = bid & (NC_ - 1);
  const int h = bh & (H_ - 1);
  const int tid = threadIdx.x, lane = tid & 63, w = tid >> 6;
  __shared__ unsigned short kh[64][72];   // k-hat [k][t]
  __shared__ unsigned short vt[64][72];   // V^T   [v][t]
  __shared__ float eps[64];
  if (tid < 64) eps[tid] = expf(td[h * S_ + tid]);
  __syncthreads();
  const int t = tid >> 2, q = (tid & 3) * 16;
  const size_t base = ((size_t)bh * T_ + c * 64 + t) * S_ + q;
  U8 k0, k1, v0, v1;
  k0.v = *(const uint4*)(kT + base);  k1.v = *(const uint4*)(kT + base + 8);
  v0.v = *(const uint4*)(vT + base);  v1.v = *(const uint4*)(vT + base + 8);
  const float mt = -(float)(63 - t);
  #pragma unroll
  for (int j = 0; j < 8; j++){
    int k = q + j;
    kh[k][t] = f2bf(bf2f(k0.s[j]) * expf(mt * eps[k]));
    vt[k][t] = v0.s[j];
  }
  #pragma unroll
  for (int j = 0; j < 8; j++){
    int k = q + 8 + j;
    kh[k][t] = f2bf(bf2f(k1.s[j]) * expf(mt * eps[k]));
    vt[k][t] = v1.s[j];
  }
  __syncthreads();
  const int ml = lane & 15, klo = (lane >> 4) * 8;
  f32x4 acc[4];
  #pragma unroll
  for (int nf = 0; nf < 4; nf++) acc[nf] = (f32x4){0.f,0.f,0.f,0.f};
  #pragma unroll
  for (int ks = 0; ks < 2; ks++){
    short8 af = *(const short8*)&vt[w*16 + ml][ks*32 + klo];
    #pragma unroll
    for (int nf = 0; nf < 4; nf++){
      short8 bfr = *(const short8*)&kh[nf*16 + ml][ks*32 + klo];
      acc[nf] = __builtin_amdgcn_mfma_f32_16x16x32_bf16(af, bfr, acc[nf], 0, 0, 0);
    }
  }
  unsigned short* dst = AS + ((size_t)bid * 64 + w*16 + (lane >> 4) * 4) * 64;
  #pragma unroll
  for (int nf = 0; nf < 4; nf++)
    #pragma unroll
    for (int r = 0; r < 4; r++)
      dst[(size_t)r * 64 + nf*16 + ml] = f2bf(acc[nf][r]);
}

// P2: chain boundary states IN PLACE: read A_c (bf16), write S_c (bf16) over it.
__global__ __launch_bounds__(256) void wkv_p2(
    unsigned short* __restrict__ AS, const float* __restrict__ td){
  const int bh = blockIdx.x >> 2, vs = blockIdx.x & 3;
  const int h = bh & (H_ - 1);
  const int tid = threadIdx.x;
  const int vo = tid >> 4, k4 = (tid & 15) * 4;
  const int v = vs * 16 + vo;
  float dL[4], S[4];
  #pragma unroll
  for (int j = 0; j < 4; j++){
    dL[j] = expf(-64.f * expf(td[h * S_ + k4 + j]));
    S[j] = 0.f;
  }
  const size_t rb = ((size_t)bh * NC_ * 64 + v) * 64 + k4;
  for (int c = 0; c < NC_; c++){
    unsigned short* p = AS + rb + (size_t)c * 4096;
    ushort4 A = *(const ushort4*)p;          // read A_c
    ushort4 o;
    o.x = f2bf(S[0]); o.y = f2bf(S[1]); o.z = f2bf(S[2]); o.w = f2bf(S[3]);
    *(ushort4*)p = o;                        // overwrite with S_c
    S[0] = fmaf(S[0], dL[0], bf2f(A.x)); S[1] = fmaf(S[1], dL[1], bf2f(A.y));
    S[2] = fmaf(S[2], dL[2], bf2f(A.z)); S[3] = fmaf(S[3], dL[3], bf2f(A.w));
  }
}

// P3: per (bh, chunk): Y = (tril(Rt Kt^T) + diag(u-term)) V + Rt S_c ; gate; emit rwkv
__global__ __launch_bounds__(256) void wkv_p3(
    const unsigned short* __restrict__ rT, const unsigned short* __restrict__ kT,
    const unsigned short* __restrict__ vT, const unsigned short* __restrict__ Sb,
    const float* __restrict__ td, const float* __restrict__ tf,
    unsigned short* __restrict__ rwkv){
  const int bid = blockIdx.x;
  const int bh = bid >> 5, c = bid & (NC_ - 1);
  const int b = bh >> 4, h = bh & (H_ - 1);
  const int tid = threadIdx.x, lane = tid & 63, w = tid >> 6;
  __shared__ unsigned short Rt[64][72];   // r * d^t        [t][k]
  __shared__ unsigned short Kt[64][72];   // k * d^{-(t+1)} [i][k] -> reused as A[t][i]
  __shared__ unsigned short Vt[64][72];   // V^T [v][t]
  __shared__ unsigned short Sc[64][72];   // S_c [v][k]
  __shared__ float eps[64], us[64], diag[64];
  __shared__ float dred[64][4];

  if (tid < 64){ eps[tid] = expf(td[h * S_ + tid]); us[tid] = tf[h * S_ + tid]; }
  __syncthreads();

  const int t = tid >> 2, q = (tid & 3) * 16;
  const size_t base  = ((size_t)bh * T_ + c * 64 + t) * S_ + q;
  const size_t sbase = (((size_t)bh * NC_ + c) * 64 + t) * 64 + q;
  {
    U8 r0, r1, k0, k1, v0, v1, s0, s1, rt0, rt1, kt0, kt1;
    r0.v = *(const uint4*)(rT + base);  r1.v = *(const uint4*)(rT + base + 8);
    k0.v = *(const uint4*)(kT + base);  k1.v = *(const uint4*)(kT + base + 8);
    v0.v = *(const uint4*)(vT + base);  v1.v = *(const uint4*)(vT + base + 8);
    s0.v = *(const uint4*)(Sb + sbase); s1.v = *(const uint4*)(Sb + sbase + 8);
    float dpart = 0.f;
    const float ft = (float)t;
    #pragma unroll
    for (int j = 0; j < 8; j++){
      int k = q + j;
      float ep = eps[k];
      float rv = bf2f(r0.s[j]), kv = bf2f(k0.s[j]);
      rt0.s[j] = f2bf(rv * expf(-ft * ep));
      kt0.s[j] = f2bf(kv * expf((ft + 1.f) * ep));
      dpart = fmaf(rv * us[k], kv, dpart);
      Vt[k][t] = v0.s[j];
    }
    #pragma unroll
    for (int j = 0; j < 8; j++){
      int k = q + 8 + j;
      float ep = eps[k];
      float rv = bf2f(r1.s[j]), kv = bf2f(k1.s[j]);
      rt1.s[j] = f2bf(rv * expf(-ft * ep));
      kt1.s[j] = f2bf(kv * expf((ft + 1.f) * ep));
      dpart = fmaf(rv * us[k], kv, dpart);
      Vt[k][t] = v1.s[j];
    }
    *(uint4*)&Rt[t][q]     = rt0.v;  *(uint4*)&Rt[t][q + 8] = rt1.v;
    *(uint4*)&Kt[t][q]     = kt0.v;  *(uint4*)&Kt[t][q + 8] = kt1.v;
    *(uint4*)&Sc[t][q]     = s0.v;   *(uint4*)&Sc[t][q + 8] = s1.v;
    dred[t][tid & 3] = dpart;
  }
  __syncthreads();
  if (tid < 64) diag[tid] = dred[tid][0] + dred[tid][1] + dred[tid][2] + dred[tid][3];

  const int ml = lane & 15, klo = (lane >> 4) * 8;
  // GEMM1: scores E[t][i]
  f32x4 acc1[4];
  #pragma unroll
  for (int nf = 0; nf < 4; nf++) acc1[nf] = (f32x4){0.f,0.f,0.f,0.f};
  #pragma unroll
  for (int ks = 0; ks < 2; ks++){
    short8 af = *(const short8*)&Rt[w*16 + ml][ks*32 + klo];
    #pragma unroll
    for (int nf = 0; nf < 4; nf++){
      short8 bfr = *(const short8*)&Kt[nf*16 + ml][ks*32 + klo];
      acc1[nf] = __builtin_amdgcn_mfma_f32_16x16x32_bf16(af, bfr, acc1[nf], 0, 0, 0);
    }
  }
  __syncthreads();   // GEMM1 reads done; diag visible

  // mask + u-diagonal, convert to bf16, store A into Kt space
  #pragma unroll
  for (int nf = 0; nf < 4; nf++){
    #pragma unroll
    for (int r = 0; r < 4; r++){
      int tt = w*16 + (lane >> 4) * 4 + r;
      int ii = nf*16 + ml;
      float e = acc1[nf][r];
      float val = (ii < tt) ? e : (ii == tt ? diag[tt] : 0.f);
      Kt[tt][ii] = f2bf(val);
    }
  }
  __syncthreads();

  // GEMM2: Y = A V + Rt S_c
  f32x4 acc2[4];
  #pragma unroll
  for (int nf = 0; nf < 4; nf++) acc2[nf] = (f32x4){0.f,0.f,0.f,0.f};
  #pragma unroll
  for (int ks = 0; ks < 2; ks++){
    short8 aA = *(const short8*)&Kt[w*16 + ml][ks*32 + klo];
    short8 aR = *(const short8*)&Rt[w*16 + ml][ks*32 + klo];
    #pragma unroll
    for (int nf = 0; nf < 4; nf++){
      short8 bV = *(const short8*)&Vt[nf*16 + ml][ks*32 + klo];
      acc2[nf] = __builtin_amdgcn_mfma_f32_16x16x32_bf16(aA, bV, acc2[nf], 0, 0, 0);
      short8 bS = *(const short8*)&Sc[nf*16 + ml][ks*32 + klo];
      acc2[nf] = __builtin_amdgcn_mfma_f32_16x16x32_bf16(aR, bS, acc2[nf], 0, 0, 0);
    }
  }

  // epilogue: gate with sigmoid(raw r), emit rwkv [B,T,C] bf16
  const size_t rrow = ((size_t)bh * T_ + c * 64) * S_;
  #pragma unroll
  for (int nf = 0; nf < 4; nf++){
    #pragma unroll
    for (int r = 0; r < 4; r++){
      int tt = w*16 + (lane >> 4) * 4 + r;
      int vv = nf*16 + ml;
      float y = acc2[nf][r];
      float rv = bf2f(rT[rrow + (size_t)tt * S_ + vv]);
      float sig = 1.f / (1.f + expf(-rv));
      rwkv[((size_t)b * T_ + c * 64 + tt) * C_ + h * S_ + vv] = f2bf(sig * y);
    }
  }
}

// ---------------- host ----------------
extern "C" void kernel_launch(void* const* d_in, const int* in_sizes, int n_in,
                              void* d_out, int out_size, void* d_ws, size_t ws_size,
                              hipStream_t stream){
  const float* x    = (const float*)d_in[0];
  const float* td   = (const float*)d_in[1];
  const float* tf   = (const float*)d_in[2];
  const float* w_r  = (const float*)d_in[3];
  const float* w_k  = (const float*)d_in[4];
  const float* w_v  = (const float*)d_in[5];
  const float* w_o  = (const float*)d_in[6];
  const float* w_fk = (const float*)d_in[7];
  const float* w_fv = (const float*)d_in[8];
  const float* g1   = (const float*)d_in[9];
  const float* b1   = (const float*)d_in[10];
  const float* g2   = (const float*)d_in[11];
  const float* b2   = (const float*)d_in[12];
  float* out = (float*)d_out;

  char* ws = (char*)d_ws;
  size_t off = 0;
  auto alloc = [&](size_t bytes){ char* p = ws + off; off += (bytes + 255) & ~(size_t)255; return p; };
  unsigned short* wrT  = (unsigned short*)alloc((size_t)C_ * C_ * 2);  // wrT,wkT,wvT contiguous -> [3072][1024]
  unsigned short* wkT  = (unsigned short*)alloc((size_t)C_ * C_ * 2);
  unsigned short* wvT  = (unsigned short*)alloc((size_t)C_ * C_ * 2);
  unsigned short* woT  = (unsigned short*)alloc((size_t)C_ * C_ * 2);
  unsigned short* wfkT = (unsigned short*)alloc((size_t)C_ * FF_ * 2);
  unsigned short* wfvT = (unsigned short*)alloc((size_t)FF_ * C_ * 2);
  unsigned short* xln  = (unsigned short*)alloc((size_t)BT_ * C_ * 2);
  unsigned short* rT   = (unsigned short*)alloc((size_t)BT_ * C_ * 2); // rT,kT,vT contiguous
  unsigned short* kT   = (unsigned short*)alloc((size_t)BT_ * C_ * 2);
  unsigned short* vT   = (unsigned short*)alloc((size_t)BT_ * C_ * 2);
  unsigned short* rwkv = (unsigned short*)alloc((size_t)BT_ * C_ * 2);
  unsigned short* hbuf = rT;   // FFN hidden reuses rT..rwkv (134MB) after scan
  unsigned short* AS   = xln;  // chunk A/S buffer reuses xln (exactly BT_*C_ bf16)

  dim3 blk(256);
  dim3 blk5(512);

  // merged weight conversions (transpose to [N][K] bf16): one launch
  wconv6_kernel<<<dim3(12288), blk, 0, stream>>>(w_r, w_k, w_v, w_o, w_fk, w_fv,
                                                 wrT, wkT, wvT, woT, wfkT, wfvT);

  // LN1
  ln_kernel<<<BT_, blk, 0, stream>>>(x, g1, b1, xln);

  // fused r|k|v projection: N=3072 -> transposed [B,H,T,S] bf16 x3
  gemm64_kernel<EPI_RKV3><<<dim3((3*C_/256)*(BT_/256)), blk5, 0, stream>>>(xln, wrT, rT, nullptr, C_, 3*C_/256);

  // WKV6 chunked scan (A/S in xln region, in-place chain)
  wkv_p1<<<B_*H_*NC_, blk, 0, stream>>>(kT, vT, td, AS);
  wkv_p2<<<B_*H_*4,   blk, 0, stream>>>(AS, td);
  wkv_p3<<<B_*H_*NC_, blk, 0, stream>>>(rT, kT, vT, AS, td, tf, rwkv);

  // output projection + residual -> d_out (fp32)
  gemm64_kernel<EPI_WO><<<dim3((C_/256)*(BT_/256)), blk5, 0, stream>>>(rwkv, woT, out, x, C_, C_/256);

  // LN2
  ln_kernel<<<BT_, blk, 0, stream>>>(out, g2, b2, xln);

  // FFN
  gemm64_kernel<EPI_FK><<<dim3((FF_/256)*(BT_/256)), blk5, 0, stream>>>(xln, wfkT, hbuf, nullptr, C_, FF_/256);
  gemm64_kernel<EPI_FV><<<dim3((C_/256)*(BT_/256)), blk5, 0, stream>>>(hbuf, wfvT, out, nullptr, FF_, C_/256);
}